// Round 3
// baseline (106.168 us; speedup 1.0000x reference)
//
#include <hip/hip_runtime.h>
#include <stdint.h>

// Causal flash-attention fwd. B=16, S=2048, D=64, fp32 in/out.
// R4: no-max softmax + split-K jobs, partials to ws, combine kernel.
// R5: exp2-folded Q scale; s_setprio around MFMA clusters.
// R6: two q-strips per wave (128 q-rows/block).
// R7: T3+T4 counted-vmcnt pipeline: 3 LDS buffers (depth-2 prefetch), raw
//     s_barrier (no vmcnt(0) drain), s_waitcnt vmcnt(4) waits only for the
//     current tile's 4 DMA loads; next tile's loads stay in flight across
//     the barrier. Strict stage-group ordering via sched_barrier(0).
//     Also: skip strip0 softmax/PV on its fully-masked last tile.
//     LDS 64KB -> 2 blocks/CU; pipeline replaces occupancy overlap.

typedef __bf16 bf16x8 __attribute__((ext_vector_type(8)));
typedef float f32x4 __attribute__((ext_vector_type(4)));

#define NB 16
#define SL 2048
#define DH 64

__device__ __forceinline__ __bf16 f2bf(float f) {
    uint32_t u = __builtin_bit_cast(uint32_t, f);
    u += 0x7FFFu + ((u >> 16) & 1u);          // RNE
    uint16_t h = (uint16_t)(u >> 16);
    return __builtin_bit_cast(__bf16, h);
}

__device__ __forceinline__ void load_lds16(const void* g, void* l) {
    __builtin_amdgcn_global_load_lds(
        (const __attribute__((address_space(1))) uint32_t*)g,
        (__attribute__((address_space(3))) uint32_t*)l, 16, 0, 0);
}

// ---------------- prepass ----------------
// Kb: [b][s][d] bf16, 16B chunk j of row s stored at j^(s&7)  (tile-contiguous)
// Vt: [b][tile][8KB image]: elem = d*64 + (j^(d&7))*8 + e  holds V[s0+8j+e][d]
__global__ __launch_bounds__(256) void prepass(
        const float* __restrict__ K, const float* __restrict__ V,
        __bf16* __restrict__ Kb, __bf16* __restrict__ Vt) {
    __shared__ float tl[64][68];
    const int b    = blockIdx.x >> 5;
    const int tile = blockIdx.x & 31;
    const int s0   = tile << 6;
    const int t    = threadIdx.x;
    const int r    = t >> 2;
    const int c0   = (t & 3) * 16;

    const float* Kp = K + ((size_t)(b * SL + s0) + r) * DH + c0;
    float4 f0 = ((const float4*)Kp)[0], f1 = ((const float4*)Kp)[1];
    float4 f2 = ((const float4*)Kp)[2], f3 = ((const float4*)Kp)[3];
    bf16x8 w0, w1;
    w0[0]=f2bf(f0.x); w0[1]=f2bf(f0.y); w0[2]=f2bf(f0.z); w0[3]=f2bf(f0.w);
    w0[4]=f2bf(f1.x); w0[5]=f2bf(f1.y); w0[6]=f2bf(f1.z); w0[7]=f2bf(f1.w);
    w1[0]=f2bf(f2.x); w1[1]=f2bf(f2.y); w1[2]=f2bf(f2.z); w1[3]=f2bf(f2.w);
    w1[4]=f2bf(f3.x); w1[5]=f2bf(f3.y); w1[6]=f2bf(f3.z); w1[7]=f2bf(f3.w);
    __bf16* Kbp = Kb + ((size_t)(b * SL + s0) + r) * DH;
    const int j0 = c0 >> 3;
    *(bf16x8*)(Kbp + ((j0       ^ (r & 7)) * 8)) = w0;
    *(bf16x8*)(Kbp + (((j0 + 1) ^ (r & 7)) * 8)) = w1;

    const float* Vp = V + ((size_t)(b * SL + s0) + r) * DH + c0;
    ((float4*)&tl[r][c0])[0] = ((const float4*)Vp)[0];
    ((float4*)&tl[r][c0])[1] = ((const float4*)Vp)[1];
    ((float4*)&tl[r][c0])[2] = ((const float4*)Vp)[2];
    ((float4*)&tl[r][c0])[3] = ((const float4*)Vp)[3];
    __syncthreads();

    __bf16* img = Vt + ((size_t)(b * 32 + tile)) * 4096;
#pragma unroll
    for (int half = 0; half < 2; ++half) {
        const int c = half * 256 + t;        // chunk 0..511
        const int d = c >> 3, slot = c & 7;
        const int jj = slot ^ (d & 7);
        bf16x8 w;
#pragma unroll
        for (int e = 0; e < 8; ++e) w[e] = f2bf(tl[jj * 8 + e][d]);
        *(bf16x8*)(img + c * 8) = w;
    }
}

// ---------------- main kernel (split-K jobs, 128 q-rows/block) ----------------
__global__ __launch_bounds__(256, 2) void attn_fwd(
        const float* __restrict__ Q, const __bf16* __restrict__ Kb,
        const __bf16* __restrict__ Vt, float* __restrict__ part,
        float* __restrict__ lpart) {
    __shared__ __align__(16) __bf16 lK[3][4096];
    __shared__ __align__(16) __bf16 lV[3][4096];
    __shared__ __align__(16) __bf16 lP[4][2048];

    // job decode: j descending so long chunks dispatch first.
    // q-block = 128 rows (qb 0..15); k-tiles nt = 2*qb+2; chunk <= 8 tiles.
    const int bid = blockIdx.x;
    const int b   = bid & 15;                 // b&7 -> XCD: K/V L2 locality
    const int j   = 39 - (bid >> 4);
    int qb, c;
    if (j < 4)        { qb = j;                 c = 0; }
    else if (j < 12)  { qb = 4 + ((j - 4) >> 1);  c = (j - 4) & 1; }
    else if (j < 24)  { int k = j - 12; qb = 8 + k / 3;    c = k % 3; }
    else              { int k = j - 24; qb = 12 + (k >> 2); c = k & 3; }
    const int nt  = 2 * qb + 2;
    const int kt0 = c * 8;
    const int kt1 = min(kt0 + 8, nt);         // every chunk has >= 2 tiles

    const int tid  = threadIdx.x;
    const int wave = tid >> 6, lane = tid & 63, quad = lane >> 4, l16 = lane & 15;
    const int xk   = l16 & 7;
    const int qg0  = qb * 128 + wave * 16 + l16;   // strip 0 q row
    const int qg1  = qg0 + 64;                     // strip 1 q row

    // Q fragments (B-frag of S^T mfma), 1/sqrt(64)*log2(e) folded -> exp2.
    const float QSC = 0.125f * 1.44269504088896340736f;
    bf16x8 qf[2][2];
#pragma unroll
    for (int st = 0; st < 2; ++st) {
        const float* qp = Q + ((size_t)b * SL + (st ? qg1 : qg0)) * DH;
#pragma unroll
        for (int s = 0; s < 2; ++s) {
            float4 a0 = ((const float4*)(qp + s * 32 + quad * 8))[0];
            float4 a1 = ((const float4*)(qp + s * 32 + quad * 8))[1];
            qf[st][s][0] = f2bf(a0.x * QSC); qf[st][s][1] = f2bf(a0.y * QSC);
            qf[st][s][2] = f2bf(a0.z * QSC); qf[st][s][3] = f2bf(a0.w * QSC);
            qf[st][s][4] = f2bf(a1.x * QSC); qf[st][s][5] = f2bf(a1.y * QSC);
            qf[st][s][6] = f2bf(a1.z * QSC); qf[st][s][7] = f2bf(a1.w * QSC);
        }
    }

    f32x4 acc0[4], acc1[4];
#pragma unroll
    for (int t = 0; t < 4; ++t) { acc0[t] = (f32x4)0.0f; acc1[t] = (f32x4)0.0f; }
    float ls0 = 0.0f, ls1 = 0.0f;

    const __bf16* Kbase = Kb + (size_t)b * SL * DH;
    const __bf16* Vbase = Vt + (size_t)b * 32 * 4096;
    __bf16* lPw = lP[wave];

    // stage one 64-key tile into buffer kt2%3 (4 DMA loads per wave)
    auto stage = [&](int kt2) {
        const int bufi = kt2 % 3;
        const __bf16* Ks = Kbase + (size_t)kt2 * 4096;
        const __bf16* Vs = Vbase + (size_t)kt2 * 4096;
#pragma unroll
        for (int i2 = 0; i2 < 2; ++i2) {
            load_lds16(Ks + (size_t)(i2 * 256 + tid) * 8,
                       &lK[bufi][(i2 * 256 + wave * 64) * 8]);
            load_lds16(Vs + (size_t)(i2 * 256 + tid) * 8,
                       &lV[bufi][(i2 * 256 + wave * 64) * 8]);
        }
    };

    // softmax: exp2 + bf16 pack + LDS store for one strip
    auto softmax_store = [&](f32x4* sc, int soff, float& ls) {
#pragma unroll
        for (int t = 0; t < 4; ++t) {
            float p0 = __builtin_amdgcn_exp2f(sc[t][0]);
            float p1 = __builtin_amdgcn_exp2f(sc[t][1]);
            float p2 = __builtin_amdgcn_exp2f(sc[t][2]);
            float p3 = __builtin_amdgcn_exp2f(sc[t][3]);
            ls += (p0 + p1) + (p2 + p3);
            uint32_t u0 = __builtin_amdgcn_perm(__builtin_bit_cast(uint32_t, p1),
                                               __builtin_bit_cast(uint32_t, p0), 0x07060302u);
            uint32_t u1 = __builtin_amdgcn_perm(__builtin_bit_cast(uint32_t, p3),
                                               __builtin_bit_cast(uint32_t, p2), 0x07060302u);
            const int cw = 2 * t + (quad >> 1);
            uint2 val; val.x = u0; val.y = u1;
            *(uint2*)&lPw[soff + l16 * 64 + ((cw ^ xk) << 3) + ((quad & 1) << 2)] = val;
        }
    };

    // prologue: Q loads first, then the two stage groups, strictly ordered so
    // vmcnt counting ("youngest 4 = next tile") holds.
    __builtin_amdgcn_sched_barrier(0);
    stage(kt0);
    __builtin_amdgcn_sched_barrier(0);
    stage(kt0 + 1);

    for (int kt = kt0; kt < kt1; ++kt) {
        // wait only for THIS tile's 4 DMA loads; tile kt+1's stay in flight
        if (kt + 1 < kt1) asm volatile("s_waitcnt vmcnt(4)" ::: "memory");
        else              asm volatile("s_waitcnt vmcnt(0)" ::: "memory");
        __builtin_amdgcn_s_barrier();          // raw: no vmcnt(0) drain
        __builtin_amdgcn_sched_barrier(0);
        if (kt + 2 < kt1) stage(kt + 2);       // depth-2 prefetch, buf (kt+2)%3

        const __bf16* K_ = lK[kt % 3];
        const __bf16* V_ = lV[kt % 3];

        // S^T = K . Q^T for both strips; kf shared across strips
        f32x4 sc0[4], sc1[4];
#pragma unroll
        for (int t = 0; t < 4; ++t) { sc0[t] = (f32x4)0.0f; sc1[t] = (f32x4)0.0f; }
        __builtin_amdgcn_s_setprio(1);
#pragma unroll
        for (int s = 0; s < 2; ++s) {
#pragma unroll
            for (int t = 0; t < 4; ++t) {
                bf16x8 kf = *(const bf16x8*)&K_[(t * 16 + l16) * 64 + (((s * 4 + quad) ^ xk) << 3)];
                sc0[t] = __builtin_amdgcn_mfma_f32_16x16x32_bf16(kf, qf[0][s], sc0[t], 0, 0, 0);
                sc1[t] = __builtin_amdgcn_mfma_f32_16x16x32_bf16(kf, qf[1][s], sc1[t], 0, 0, 0);
            }
        }
        __builtin_amdgcn_s_setprio(0);

        // causal mask (strip0 diag tile = 2qb; strip1 diag = 2qb+1 = nt-1)
        if (kt >= 2 * qb) {
            const int kb = kt * 64;
#pragma unroll
            for (int t = 0; t < 4; ++t)
#pragma unroll
                for (int r = 0; r < 4; ++r) {
                    const int key = kb + t * 16 + quad * 4 + r;
                    if (key > qg0) sc0[t][r] = -1.0e30f;
                    if (key > qg1) sc1[t][r] = -1.0e30f;
                }
        }

        const bool s0live = (kt != nt - 1);    // strip0 fully masked on last tile
        if (s0live) softmax_store(sc0, 0, ls0);
        softmax_store(sc1, 1024, ls1);
        asm volatile("" ::: "memory");         // same-wave LDS write->read order

        bf16x8 pf10 = *(const bf16x8*)&lPw[1024 + l16 * 64 + (((0 + quad) ^ xk) << 3)];
        bf16x8 pf11 = *(const bf16x8*)&lPw[1024 + l16 * 64 + (((4 + quad) ^ xk) << 3)];

        __builtin_amdgcn_s_setprio(1);
        if (s0live) {
            bf16x8 pf00 = *(const bf16x8*)&lPw[l16 * 64 + (((0 + quad) ^ xk) << 3)];
            bf16x8 pf01 = *(const bf16x8*)&lPw[l16 * 64 + (((4 + quad) ^ xk) << 3)];
#pragma unroll
            for (int t = 0; t < 4; ++t) {
                bf16x8 vf = *(const bf16x8*)&V_[(t * 16 + l16) * 64 + (((0 + quad) ^ xk) << 3)];
                acc0[t] = __builtin_amdgcn_mfma_f32_16x16x32_bf16(vf, pf00, acc0[t], 0, 0, 0);
                acc1[t] = __builtin_amdgcn_mfma_f32_16x16x32_bf16(vf, pf10, acc1[t], 0, 0, 0);
            }
#pragma unroll
            for (int t = 0; t < 4; ++t) {
                bf16x8 vf = *(const bf16x8*)&V_[(t * 16 + l16) * 64 + (((4 + quad) ^ xk) << 3)];
                acc0[t] = __builtin_amdgcn_mfma_f32_16x16x32_bf16(vf, pf01, acc0[t], 0, 0, 0);
                acc1[t] = __builtin_amdgcn_mfma_f32_16x16x32_bf16(vf, pf11, acc1[t], 0, 0, 0);
            }
        } else {
#pragma unroll
            for (int t = 0; t < 4; ++t) {
                bf16x8 vf = *(const bf16x8*)&V_[(t * 16 + l16) * 64 + (((0 + quad) ^ xk) << 3)];
                acc1[t] = __builtin_amdgcn_mfma_f32_16x16x32_bf16(vf, pf10, acc1[t], 0, 0, 0);
            }
#pragma unroll
            for (int t = 0; t < 4; ++t) {
                bf16x8 vf = *(const bf16x8*)&V_[(t * 16 + l16) * 64 + (((4 + quad) ^ xk) << 3)];
                acc1[t] = __builtin_amdgcn_mfma_f32_16x16x32_bf16(vf, pf11, acc1[t], 0, 0, 0);
            }
        }
        __builtin_amdgcn_s_setprio(0);
    }

    // row-sum l: reduce across the 4 quads (lanes l16 ^ {16,32})
    ls0 += __shfl_xor(ls0, 16); ls0 += __shfl_xor(ls0, 32);
    ls1 += __shfl_xor(ls1, 16); ls1 += __shfl_xor(ls1, 32);

    // partial epilogue: lane owns rows qg0/qg1, d = t*16 + quad*4 + {0..3}
    float* pp0 = part + ((size_t)(b * SL + qg0) * 4 + c) * DH + quad * 4;
    float* pp1 = part + ((size_t)(b * SL + qg1) * 4 + c) * DH + quad * 4;
#pragma unroll
    for (int t = 0; t < 4; ++t) {
        float4 o4;
        o4.x = acc0[t][0]; o4.y = acc0[t][1]; o4.z = acc0[t][2]; o4.w = acc0[t][3];
        *(float4*)(pp0 + t * 16) = o4;
        o4.x = acc1[t][0]; o4.y = acc1[t][1]; o4.z = acc1[t][2]; o4.w = acc1[t][3];
        *(float4*)(pp1 + t * 16) = o4;
    }
    if (quad == 0) {
        lpart[(size_t)(b * SL + qg0) * 4 + c] = ls0;
        lpart[(size_t)(b * SL + qg1) * 4 + c] = ls1;
    }
}

// ---------------- combine ----------------
__global__ __launch_bounds__(256) void combine(
        const float* __restrict__ part, const float* __restrict__ lpart,
        float* __restrict__ O) {
    const int tid = threadIdx.x;
    const int r   = blockIdx.x * 16 + (tid >> 4);   // global row (b*2048+row)
    const int d4  = tid & 15;
    const int qb  = (r >> 7) & 15;
    const int nch = (2 * qb + 9) >> 3;              // ceil((2qb+2)/8)
    float4 s = make_float4(0.f, 0.f, 0.f, 0.f);
    float ls = 0.f;
    for (int c = 0; c < nch; ++c) {
        float4 p = *(const float4*)(part + ((size_t)r * 4 + c) * DH + d4 * 4);
        s.x += p.x; s.y += p.y; s.z += p.z; s.w += p.w;
        ls += lpart[(size_t)r * 4 + c];
    }
    const float inv = 1.0f / ls;
    float4 o; o.x = s.x * inv; o.y = s.y * inv; o.z = s.z * inv; o.w = s.w * inv;
    *(float4*)(O + (size_t)r * DH + d4 * 4) = o;
}

extern "C" void kernel_launch(void* const* d_in, const int* in_sizes, int n_in,
                              void* d_out, int out_size, void* d_ws, size_t ws_size,
                              hipStream_t stream) {
    const float* q = (const float*)d_in[0];
    const float* k = (const float*)d_in[1];
    const float* v = (const float*)d_in[2];
    float* o = (float*)d_out;
    __bf16* Kb   = (__bf16*)d_ws;                          // 4 MiB
    __bf16* Vt   = Kb + (size_t)NB * SL * DH;              // 4 MiB
    float*  pt   = (float*)((char*)d_ws + (8u << 20));     // 32 MiB partials
    float*  lp   = pt + (size_t)NB * SL * 4 * DH;          // 512 KiB
    hipLaunchKernelGGL(prepass, dim3(NB * 32), dim3(256), 0, stream, k, v, Kb, Vt);
    hipLaunchKernelGGL(attn_fwd, dim3(640), dim3(256), 0, stream, q, Kb, Vt, pt, lp);
    hipLaunchKernelGGL(combine, dim3(NB * SL / 16), dim3(256), 0, stream, pt, lp, o);
}

// Round 4
// 103.830 us; speedup vs baseline: 1.0225x; 1.0225x over previous
//
#include <hip/hip_runtime.h>
#include <stdint.h>

// Causal flash-attention fwd. B=16, S=2048, D=64, fp32 in/out.
// R4: no-max softmax + split-K jobs, partials to ws, combine kernel.
// R5: exp2-folded Q scale; s_setprio around MFMA clusters.
// R6: two q-strips per wave (128 q-rows/block).
// R7 (REVERTED): counted-vmcnt pipeline regressed 6% (occupancy 3->2 + sched pinning).
// R8: NO K/V LDS staging at all. K/V working set is L2-resident (512KB/batch,
//     2 batches/XCD << 4MB L2), so kf/vf fragments are read directly from
//     global (L2 hit ~200cy, hidden by 12 waves/CU of independent dataflow).
//     Removes every __syncthreads / global_load_lds / vmcnt from the loop;
//     waves run free, compiler can hoist next-tile loads under PV MFMAs.
//     LDS = P buffers only (16KB).

typedef __bf16 bf16x8 __attribute__((ext_vector_type(8)));
typedef float f32x4 __attribute__((ext_vector_type(4)));

#define NB 16
#define SL 2048
#define DH 64

__device__ __forceinline__ __bf16 f2bf(float f) {
    uint32_t u = __builtin_bit_cast(uint32_t, f);
    u += 0x7FFFu + ((u >> 16) & 1u);          // RNE
    uint16_t h = (uint16_t)(u >> 16);
    return __builtin_bit_cast(__bf16, h);
}

// ---------------- prepass ----------------
// Kb: [b][s][d] bf16, 16B chunk j of row s stored at j^(s&7)  (tile-contiguous)
// Vt: [b][tile][8KB image]: elem = d*64 + (j^(d&7))*8 + e  holds V[s0+8j+e][d]
__global__ __launch_bounds__(256) void prepass(
        const float* __restrict__ K, const float* __restrict__ V,
        __bf16* __restrict__ Kb, __bf16* __restrict__ Vt) {
    __shared__ float tl[64][68];
    const int b    = blockIdx.x >> 5;
    const int tile = blockIdx.x & 31;
    const int s0   = tile << 6;
    const int t    = threadIdx.x;
    const int r    = t >> 2;
    const int c0   = (t & 3) * 16;

    const float* Kp = K + ((size_t)(b * SL + s0) + r) * DH + c0;
    float4 f0 = ((const float4*)Kp)[0], f1 = ((const float4*)Kp)[1];
    float4 f2 = ((const float4*)Kp)[2], f3 = ((const float4*)Kp)[3];
    bf16x8 w0, w1;
    w0[0]=f2bf(f0.x); w0[1]=f2bf(f0.y); w0[2]=f2bf(f0.z); w0[3]=f2bf(f0.w);
    w0[4]=f2bf(f1.x); w0[5]=f2bf(f1.y); w0[6]=f2bf(f1.z); w0[7]=f2bf(f1.w);
    w1[0]=f2bf(f2.x); w1[1]=f2bf(f2.y); w1[2]=f2bf(f2.z); w1[3]=f2bf(f2.w);
    w1[4]=f2bf(f3.x); w1[5]=f2bf(f3.y); w1[6]=f2bf(f3.z); w1[7]=f2bf(f3.w);
    __bf16* Kbp = Kb + ((size_t)(b * SL + s0) + r) * DH;
    const int j0 = c0 >> 3;
    *(bf16x8*)(Kbp + ((j0       ^ (r & 7)) * 8)) = w0;
    *(bf16x8*)(Kbp + (((j0 + 1) ^ (r & 7)) * 8)) = w1;

    const float* Vp = V + ((size_t)(b * SL + s0) + r) * DH + c0;
    ((float4*)&tl[r][c0])[0] = ((const float4*)Vp)[0];
    ((float4*)&tl[r][c0])[1] = ((const float4*)Vp)[1];
    ((float4*)&tl[r][c0])[2] = ((const float4*)Vp)[2];
    ((float4*)&tl[r][c0])[3] = ((const float4*)Vp)[3];
    __syncthreads();

    __bf16* img = Vt + ((size_t)(b * 32 + tile)) * 4096;
#pragma unroll
    for (int half = 0; half < 2; ++half) {
        const int c = half * 256 + t;        // chunk 0..511
        const int d = c >> 3, slot = c & 7;
        const int jj = slot ^ (d & 7);
        bf16x8 w;
#pragma unroll
        for (int e = 0; e < 8; ++e) w[e] = f2bf(tl[jj * 8 + e][d]);
        *(bf16x8*)(img + c * 8) = w;
    }
}

// ---------------- main kernel (split-K jobs, 128 q-rows/block) ----------------
__global__ __launch_bounds__(256, 3) void attn_fwd(
        const float* __restrict__ Q, const __bf16* __restrict__ Kb,
        const __bf16* __restrict__ Vt, float* __restrict__ part,
        float* __restrict__ lpart) {
    __shared__ __align__(16) __bf16 lP[4][2048];

    // job decode: j descending so long chunks dispatch first.
    // q-block = 128 rows (qb 0..15); k-tiles nt = 2*qb+2; chunk <= 8 tiles.
    const int bid = blockIdx.x;
    const int b   = bid & 15;                 // b&7 -> XCD: K/V L2 locality
    const int j   = 39 - (bid >> 4);
    int qb, c;
    if (j < 4)        { qb = j;                 c = 0; }
    else if (j < 12)  { qb = 4 + ((j - 4) >> 1);  c = (j - 4) & 1; }
    else if (j < 24)  { int k = j - 12; qb = 8 + k / 3;    c = k % 3; }
    else              { int k = j - 24; qb = 12 + (k >> 2); c = k & 3; }
    const int nt  = 2 * qb + 2;
    const int kt0 = c * 8;
    const int kt1 = min(kt0 + 8, nt);

    const int tid  = threadIdx.x;
    const int wave = tid >> 6, lane = tid & 63, quad = lane >> 4, l16 = lane & 15;
    const int xk   = l16 & 7;
    const int qg0  = qb * 128 + wave * 16 + l16;   // strip 0 q row
    const int qg1  = qg0 + 64;                     // strip 1 q row

    // Q fragments (B-frag of S^T mfma), 1/sqrt(64)*log2(e) folded -> exp2.
    const float QSC = 0.125f * 1.44269504088896340736f;
    bf16x8 qf[2][2];
#pragma unroll
    for (int st = 0; st < 2; ++st) {
        const float* qp = Q + ((size_t)b * SL + (st ? qg1 : qg0)) * DH;
#pragma unroll
        for (int s = 0; s < 2; ++s) {
            float4 a0 = ((const float4*)(qp + s * 32 + quad * 8))[0];
            float4 a1 = ((const float4*)(qp + s * 32 + quad * 8))[1];
            qf[st][s][0] = f2bf(a0.x * QSC); qf[st][s][1] = f2bf(a0.y * QSC);
            qf[st][s][2] = f2bf(a0.z * QSC); qf[st][s][3] = f2bf(a0.w * QSC);
            qf[st][s][4] = f2bf(a1.x * QSC); qf[st][s][5] = f2bf(a1.y * QSC);
            qf[st][s][6] = f2bf(a1.z * QSC); qf[st][s][7] = f2bf(a1.w * QSC);
        }
    }

    f32x4 acc0[4], acc1[4];
#pragma unroll
    for (int t = 0; t < 4; ++t) { acc0[t] = (f32x4)0.0f; acc1[t] = (f32x4)0.0f; }
    float ls0 = 0.0f, ls1 = 0.0f;

    const __bf16* Kbase = Kb + (size_t)b * SL * DH;
    const __bf16* Vbase = Vt + (size_t)b * 32 * 4096;
    __bf16* lPw = lP[wave];

    // softmax: exp2 + bf16 pack + LDS store for one strip
    auto softmax_store = [&](f32x4* sc, int soff, float& ls) {
#pragma unroll
        for (int t = 0; t < 4; ++t) {
            float p0 = __builtin_amdgcn_exp2f(sc[t][0]);
            float p1 = __builtin_amdgcn_exp2f(sc[t][1]);
            float p2 = __builtin_amdgcn_exp2f(sc[t][2]);
            float p3 = __builtin_amdgcn_exp2f(sc[t][3]);
            ls += (p0 + p1) + (p2 + p3);
            uint32_t u0 = __builtin_amdgcn_perm(__builtin_bit_cast(uint32_t, p1),
                                               __builtin_bit_cast(uint32_t, p0), 0x07060302u);
            uint32_t u1 = __builtin_amdgcn_perm(__builtin_bit_cast(uint32_t, p3),
                                               __builtin_bit_cast(uint32_t, p2), 0x07060302u);
            const int cw = 2 * t + (quad >> 1);
            uint2 val; val.x = u0; val.y = u1;
            *(uint2*)&lPw[soff + l16 * 64 + ((cw ^ xk) << 3) + ((quad & 1) << 2)] = val;
        }
    };

    for (int kt = kt0; kt < kt1; ++kt) {
        // K/V tiles read straight from global (L2-resident); no LDS, no barrier.
        const __bf16* K_ = Kbase + (size_t)kt * 4096;
        const __bf16* V_ = Vbase + (size_t)kt * 4096;

        // S^T = K . Q^T for both strips; kf shared across strips
        f32x4 sc0[4], sc1[4];
#pragma unroll
        for (int t = 0; t < 4; ++t) { sc0[t] = (f32x4)0.0f; sc1[t] = (f32x4)0.0f; }
        __builtin_amdgcn_s_setprio(1);
#pragma unroll
        for (int s = 0; s < 2; ++s) {
#pragma unroll
            for (int t = 0; t < 4; ++t) {
                bf16x8 kf = *(const bf16x8*)&K_[(t * 16 + l16) * 64 + (((s * 4 + quad) ^ xk) << 3)];
                sc0[t] = __builtin_amdgcn_mfma_f32_16x16x32_bf16(kf, qf[0][s], sc0[t], 0, 0, 0);
                sc1[t] = __builtin_amdgcn_mfma_f32_16x16x32_bf16(kf, qf[1][s], sc1[t], 0, 0, 0);
            }
        }
        __builtin_amdgcn_s_setprio(0);

        // causal mask (strip0 diag tile = 2qb; strip1 diag = 2qb+1 = nt-1)
        if (kt >= 2 * qb) {
            const int kb = kt * 64;
#pragma unroll
            for (int t = 0; t < 4; ++t)
#pragma unroll
                for (int r = 0; r < 4; ++r) {
                    const int key = kb + t * 16 + quad * 4 + r;
                    if (key > qg0) sc0[t][r] = -1.0e30f;
                    if (key > qg1) sc1[t][r] = -1.0e30f;
                }
        }

        const bool s0live = (kt != nt - 1);    // strip0 fully masked on last tile
        if (s0live) softmax_store(sc0, 0, ls0);
        softmax_store(sc1, 1024, ls1);
        asm volatile("" ::: "memory");         // same-wave LDS write->read order

        bf16x8 pf10 = *(const bf16x8*)&lPw[1024 + l16 * 64 + (((0 + quad) ^ xk) << 3)];
        bf16x8 pf11 = *(const bf16x8*)&lPw[1024 + l16 * 64 + (((4 + quad) ^ xk) << 3)];

        __builtin_amdgcn_s_setprio(1);
        if (s0live) {
            bf16x8 pf00 = *(const bf16x8*)&lPw[l16 * 64 + (((0 + quad) ^ xk) << 3)];
            bf16x8 pf01 = *(const bf16x8*)&lPw[l16 * 64 + (((4 + quad) ^ xk) << 3)];
#pragma unroll
            for (int t = 0; t < 4; ++t) {
                bf16x8 vf = *(const bf16x8*)&V_[(t * 16 + l16) * 64 + (((0 + quad) ^ xk) << 3)];
                acc0[t] = __builtin_amdgcn_mfma_f32_16x16x32_bf16(vf, pf00, acc0[t], 0, 0, 0);
                acc1[t] = __builtin_amdgcn_mfma_f32_16x16x32_bf16(vf, pf10, acc1[t], 0, 0, 0);
            }
#pragma unroll
            for (int t = 0; t < 4; ++t) {
                bf16x8 vf = *(const bf16x8*)&V_[(t * 16 + l16) * 64 + (((4 + quad) ^ xk) << 3)];
                acc0[t] = __builtin_amdgcn_mfma_f32_16x16x32_bf16(vf, pf01, acc0[t], 0, 0, 0);
                acc1[t] = __builtin_amdgcn_mfma_f32_16x16x32_bf16(vf, pf11, acc1[t], 0, 0, 0);
            }
        } else {
#pragma unroll
            for (int t = 0; t < 4; ++t) {
                bf16x8 vf = *(const bf16x8*)&V_[(t * 16 + l16) * 64 + (((0 + quad) ^ xk) << 3)];
                acc1[t] = __builtin_amdgcn_mfma_f32_16x16x32_bf16(vf, pf10, acc1[t], 0, 0, 0);
            }
#pragma unroll
            for (int t = 0; t < 4; ++t) {
                bf16x8 vf = *(const bf16x8*)&V_[(t * 16 + l16) * 64 + (((4 + quad) ^ xk) << 3)];
                acc1[t] = __builtin_amdgcn_mfma_f32_16x16x32_bf16(vf, pf11, acc1[t], 0, 0, 0);
            }
        }
        __builtin_amdgcn_s_setprio(0);
    }

    // row-sum l: reduce across the 4 quads (lanes l16 ^ {16,32})
    ls0 += __shfl_xor(ls0, 16); ls0 += __shfl_xor(ls0, 32);
    ls1 += __shfl_xor(ls1, 16); ls1 += __shfl_xor(ls1, 32);

    // partial epilogue: lane owns rows qg0/qg1, d = t*16 + quad*4 + {0..3}
    float* pp0 = part + ((size_t)(b * SL + qg0) * 4 + c) * DH + quad * 4;
    float* pp1 = part + ((size_t)(b * SL + qg1) * 4 + c) * DH + quad * 4;
#pragma unroll
    for (int t = 0; t < 4; ++t) {
        float4 o4;
        o4.x = acc0[t][0]; o4.y = acc0[t][1]; o4.z = acc0[t][2]; o4.w = acc0[t][3];
        *(float4*)(pp0 + t * 16) = o4;
        o4.x = acc1[t][0]; o4.y = acc1[t][1]; o4.z = acc1[t][2]; o4.w = acc1[t][3];
        *(float4*)(pp1 + t * 16) = o4;
    }
    if (quad == 0) {
        lpart[(size_t)(b * SL + qg0) * 4 + c] = ls0;
        lpart[(size_t)(b * SL + qg1) * 4 + c] = ls1;
    }
}

// ---------------- combine ----------------
__global__ __launch_bounds__(256) void combine(
        const float* __restrict__ part, const float* __restrict__ lpart,
        float* __restrict__ O) {
    const int tid = threadIdx.x;
    const int r   = blockIdx.x * 16 + (tid >> 4);   // global row (b*2048+row)
    const int d4  = tid & 15;
    const int qb  = (r >> 7) & 15;
    const int nch = (2 * qb + 9) >> 3;              // ceil((2qb+2)/8)
    float4 s = make_float4(0.f, 0.f, 0.f, 0.f);
    float ls = 0.f;
    for (int c = 0; c < nch; ++c) {
        float4 p = *(const float4*)(part + ((size_t)r * 4 + c) * DH + d4 * 4);
        s.x += p.x; s.y += p.y; s.z += p.z; s.w += p.w;
        ls += lpart[(size_t)r * 4 + c];
    }
    const float inv = 1.0f / ls;
    float4 o; o.x = s.x * inv; o.y = s.y * inv; o.z = s.z * inv; o.w = s.w * inv;
    *(float4*)(O + (size_t)r * DH + d4 * 4) = o;
}

extern "C" void kernel_launch(void* const* d_in, const int* in_sizes, int n_in,
                              void* d_out, int out_size, void* d_ws, size_t ws_size,
                              hipStream_t stream) {
    const float* q = (const float*)d_in[0];
    const float* k = (const float*)d_in[1];
    const float* v = (const float*)d_in[2];
    float* o = (float*)d_out;
    __bf16* Kb   = (__bf16*)d_ws;                          // 4 MiB
    __bf16* Vt   = Kb + (size_t)NB * SL * DH;              // 4 MiB
    float*  pt   = (float*)((char*)d_ws + (8u << 20));     // 32 MiB partials
    float*  lp   = pt + (size_t)NB * SL * 4 * DH;          // 512 KiB
    hipLaunchKernelGGL(prepass, dim3(NB * 32), dim3(256), 0, stream, k, v, Kb, Vt);
    hipLaunchKernelGGL(attn_fwd, dim3(640), dim3(256), 0, stream, q, Kb, Vt, pt, lp);
    hipLaunchKernelGGL(combine, dim3(NB * SL / 16), dim3(256), 0, stream, pt, lp, o);
}

// Round 5
// 97.110 us; speedup vs baseline: 1.0933x; 1.0692x over previous
//
#include <hip/hip_runtime.h>
#include <stdint.h>

// Causal flash-attention fwd. B=16, S=2048, D=64, fp32 in/out.
// R4: no-max softmax + split-K jobs, partials to ws, combine kernel.
// R5: exp2-folded Q scale; s_setprio around MFMA clusters.
// R6: 128 q-rows/block.
// R7 (REVERTED): counted-vmcnt pipeline (-6%: occupancy + sched pinning).
// R8 (REVERTED): direct-L2 K/V (-4%: LDS staging wins).
// R9: T12 in-register softmax. 32x32 swapped QK (mfma(K,Q)): each lane holds
//     P for one q-row in regs -> mask/exp2 in-register -> PV A-frags built
//     with 16 cvt_pk + 8 permlane32_swap. No P-LDS round trip, no fence,
//     lP freed (LDS 48->32KB). MFMA instrs 32->16/tile-wave, LDS ops 28->16.

typedef __bf16 bf16x8 __attribute__((ext_vector_type(8)));
typedef float f32x4 __attribute__((ext_vector_type(4)));
typedef float f32x16 __attribute__((ext_vector_type(16)));
typedef uint32_t u32x4 __attribute__((ext_vector_type(4)));

#define NB 16
#define SL 2048
#define DH 64

__device__ __forceinline__ __bf16 f2bf(float f) {
    uint32_t u = __builtin_bit_cast(uint32_t, f);
    u += 0x7FFFu + ((u >> 16) & 1u);          // RNE
    uint16_t h = (uint16_t)(u >> 16);
    return __builtin_bit_cast(__bf16, h);
}

__device__ __forceinline__ uint32_t cvtpk(float lo, float hi) {
    uint32_t r;
    asm("v_cvt_pk_bf16_f32 %0, %1, %2" : "=v"(r) : "v"(lo), "v"(hi));
    return r;
}

__device__ __forceinline__ void load_lds16(const void* g, void* l) {
    __builtin_amdgcn_global_load_lds(
        (const __attribute__((address_space(1))) uint32_t*)g,
        (__attribute__((address_space(3))) uint32_t*)l, 16, 0, 0);
}

// ---------------- prepass ----------------
// Kb: [b][s][d] bf16, 16B chunk j of row s stored at j^(s&7)  (tile-contiguous)
// Vt: [b][tile][8KB image]: elem = d*64 + (j^(d&7))*8 + e  holds V[s0+8j+e][d]
__global__ __launch_bounds__(256) void prepass(
        const float* __restrict__ K, const float* __restrict__ V,
        __bf16* __restrict__ Kb, __bf16* __restrict__ Vt) {
    __shared__ float tl[64][68];
    const int b    = blockIdx.x >> 5;
    const int tile = blockIdx.x & 31;
    const int s0   = tile << 6;
    const int t    = threadIdx.x;
    const int r    = t >> 2;
    const int c0   = (t & 3) * 16;

    const float* Kp = K + ((size_t)(b * SL + s0) + r) * DH + c0;
    float4 f0 = ((const float4*)Kp)[0], f1 = ((const float4*)Kp)[1];
    float4 f2 = ((const float4*)Kp)[2], f3 = ((const float4*)Kp)[3];
    bf16x8 w0, w1;
    w0[0]=f2bf(f0.x); w0[1]=f2bf(f0.y); w0[2]=f2bf(f0.z); w0[3]=f2bf(f0.w);
    w0[4]=f2bf(f1.x); w0[5]=f2bf(f1.y); w0[6]=f2bf(f1.z); w0[7]=f2bf(f1.w);
    w1[0]=f2bf(f2.x); w1[1]=f2bf(f2.y); w1[2]=f2bf(f2.z); w1[3]=f2bf(f2.w);
    w1[4]=f2bf(f3.x); w1[5]=f2bf(f3.y); w1[6]=f2bf(f3.z); w1[7]=f2bf(f3.w);
    __bf16* Kbp = Kb + ((size_t)(b * SL + s0) + r) * DH;
    const int j0 = c0 >> 3;
    *(bf16x8*)(Kbp + ((j0       ^ (r & 7)) * 8)) = w0;
    *(bf16x8*)(Kbp + (((j0 + 1) ^ (r & 7)) * 8)) = w1;

    const float* Vp = V + ((size_t)(b * SL + s0) + r) * DH + c0;
    ((float4*)&tl[r][c0])[0] = ((const float4*)Vp)[0];
    ((float4*)&tl[r][c0])[1] = ((const float4*)Vp)[1];
    ((float4*)&tl[r][c0])[2] = ((const float4*)Vp)[2];
    ((float4*)&tl[r][c0])[3] = ((const float4*)Vp)[3];
    __syncthreads();

    __bf16* img = Vt + ((size_t)(b * 32 + tile)) * 4096;
#pragma unroll
    for (int half = 0; half < 2; ++half) {
        const int c = half * 256 + t;        // chunk 0..511
        const int d = c >> 3, slot = c & 7;
        const int jj = slot ^ (d & 7);
        bf16x8 w;
#pragma unroll
        for (int e = 0; e < 8; ++e) w[e] = f2bf(tl[jj * 8 + e][d]);
        *(bf16x8*)(img + c * 8) = w;
    }
}

// ---------------- main kernel (split-K jobs, 128 q-rows/block) ----------------
__global__ __launch_bounds__(256, 4) void attn_fwd(
        const float* __restrict__ Q, const __bf16* __restrict__ Kb,
        const __bf16* __restrict__ Vt, float* __restrict__ part,
        float* __restrict__ lpart) {
    __shared__ __align__(16) __bf16 lK[2][4096];
    __shared__ __align__(16) __bf16 lV[2][4096];

    // job decode: j descending so long chunks dispatch first.
    // q-block = 128 rows (qb 0..15); k-tiles nt = 2*qb+2; chunk <= 8 tiles.
    const int bid = blockIdx.x;
    const int b   = bid & 15;                 // b&7 -> XCD: K/V L2 locality
    const int j   = 39 - (bid >> 4);
    int qb, c;
    if (j < 4)        { qb = j;                 c = 0; }
    else if (j < 12)  { qb = 4 + ((j - 4) >> 1);  c = (j - 4) & 1; }
    else if (j < 24)  { int k = j - 12; qb = 8 + k / 3;    c = k % 3; }
    else              { int k = j - 24; qb = 12 + (k >> 2); c = k & 3; }
    const int nt  = 2 * qb + 2;
    const int kt0 = c * 8;
    const int kt1 = min(kt0 + 8, nt);

    const int tid  = threadIdx.x;
    const int wave = tid >> 6, lane = tid & 63;
    const int h    = lane >> 5, l32 = lane & 31, x8 = lane & 7;
    const int qg   = qb * 128 + wave * 32 + l32;   // this lane's q row
    const int dt   = 2 * qb + (wave >> 1);         // first tile needing mask

    // Q B-frag (32x32x16): col=lane&31=q row, k = h*8+e per d-subtile s4.
    // 1/sqrt(64)*log2(e) folded -> exp2.
    const float QSC = 0.125f * 1.44269504088896340736f;
    bf16x8 qf[4];
    const float* qp = Q + ((size_t)b * SL + qg) * DH + h * 8;
#pragma unroll
    for (int s4 = 0; s4 < 4; ++s4) {
        float4 a0 = ((const float4*)(qp + s4 * 16))[0];
        float4 a1 = ((const float4*)(qp + s4 * 16))[1];
        qf[s4][0] = f2bf(a0.x * QSC); qf[s4][1] = f2bf(a0.y * QSC);
        qf[s4][2] = f2bf(a0.z * QSC); qf[s4][3] = f2bf(a0.w * QSC);
        qf[s4][4] = f2bf(a1.x * QSC); qf[s4][5] = f2bf(a1.y * QSC);
        qf[s4][6] = f2bf(a1.z * QSC); qf[s4][7] = f2bf(a1.w * QSC);
    }

    f32x16 acc0 = (f32x16)0.0f, acc1 = (f32x16)0.0f;   // O[q][d], dh=0/1
    float ls = 0.0f;

    const __bf16* Kbase = Kb + (size_t)b * SL * DH;
    const __bf16* Vbase = Vt + (size_t)b * 32 * 4096;

    auto stage = [&](int kt2) {
        const int bufi = kt2 & 1;
        const __bf16* Ks = Kbase + (size_t)kt2 * 4096;
        const __bf16* Vs = Vbase + (size_t)kt2 * 4096;
#pragma unroll
        for (int i2 = 0; i2 < 2; ++i2) {
            load_lds16(Ks + (size_t)(i2 * 256 + tid) * 8,
                       &lK[bufi][(i2 * 256 + wave * 64) * 8]);
            load_lds16(Vs + (size_t)(i2 * 256 + tid) * 8,
                       &lV[bufi][(i2 * 256 + wave * 64) * 8]);
        }
    };

    stage(kt0);
    for (int kt = kt0; kt < kt1; ++kt) {
        __syncthreads();                   // own DMA drained; prev tile consumed
        if (kt + 1 < kt1) stage(kt + 1);
        const __bf16* K_ = lK[kt & 1];
        const __bf16* V_ = lV[kt & 1];

        // waves 0,1 are fully masked on the last tile of the diagonal chunk
        const bool skip = (wave < 2) && (kt == nt - 1);
        if (!skip) {
            // S^T = K . Q^T (swapped): C[key][q], col=lane&31=q,
            // key = g*32 + (r&3) + 8*(r>>2) + 4*h  in regs r of sc{g}
            f32x16 sc0 = (f32x16)0.0f, sc1 = (f32x16)0.0f;
            __builtin_amdgcn_s_setprio(1);
#pragma unroll
            for (int s4 = 0; s4 < 4; ++s4) {
                bf16x8 kf0 = *(const bf16x8*)&K_[(l32)      * 64 + (((s4 * 2 + h) ^ x8) << 3)];
                bf16x8 kf1 = *(const bf16x8*)&K_[(32 + l32) * 64 + (((s4 * 2 + h) ^ x8) << 3)];
                sc0 = __builtin_amdgcn_mfma_f32_32x32x16_bf16(kf0, qf[s4], sc0, 0, 0, 0);
                sc1 = __builtin_amdgcn_mfma_f32_32x32x16_bf16(kf1, qf[s4], sc1, 0, 0, 0);
            }
            __builtin_amdgcn_s_setprio(0);

            // causal mask on diagonal tiles
            if (kt >= dt) {
                const int kb = kt * 64;
#pragma unroll
                for (int r = 0; r < 16; ++r) {
                    const int krow = (r & 3) + 8 * (r >> 2) + 4 * h;
                    if (kb + krow > qg)      sc0[r] = -1.0e30f;
                    if (kb + 32 + krow > qg) sc1[r] = -1.0e30f;
                }
            }

            // P = exp2(S) in-register; row-sum accumulates (keys split h/h^1)
#pragma unroll
            for (int r = 0; r < 16; ++r) {
                sc0[r] = __builtin_amdgcn_exp2f(sc0[r]);
                sc1[r] = __builtin_amdgcn_exp2f(sc1[r]);
                ls += sc0[r] + sc1[r];
            }

            // Build PV A-frags: lane needs P[q=l32][keys ks*16 + h*8 + 0..7].
            // cvt_pk packs pairs; permlane32_swap exchanges with lane^32.
            bf16x8 af[4];
#pragma unroll
            for (int ks = 0; ks < 4; ++ks) {
                const int jj = (ks & 1) * 8;
                const f32x16& sg = (ks & 2) ? sc1 : sc0;
                uint32_t u0 = cvtpk(sg[jj + 0], sg[jj + 1]);
                uint32_t u1 = cvtpk(sg[jj + 2], sg[jj + 3]);
                uint32_t u2 = cvtpk(sg[jj + 4], sg[jj + 5]);
                uint32_t u3 = cvtpk(sg[jj + 6], sg[jj + 7]);
                auto r0 = __builtin_amdgcn_permlane32_swap(u0, u2, false, false);
                auto r1 = __builtin_amdgcn_permlane32_swap(u1, u3, false, false);
                u32x4 w; w[0] = r0[0]; w[1] = r1[0]; w[2] = r0[1]; w[3] = r1[1];
                af[ks] = __builtin_bit_cast(bf16x8, w);
            }

            // O += P . V : B-frag vf has col=lane&31=d, k = h*8+e
            __builtin_amdgcn_s_setprio(1);
#pragma unroll
            for (int ks = 0; ks < 4; ++ks) {
                bf16x8 vf0 = *(const bf16x8*)&V_[(l32)      * 64 + ((((ks << 1) + h) ^ x8) << 3)];
                bf16x8 vf1 = *(const bf16x8*)&V_[(32 + l32) * 64 + ((((ks << 1) + h) ^ x8) << 3)];
                acc0 = __builtin_amdgcn_mfma_f32_32x32x16_bf16(af[ks], vf0, acc0, 0, 0, 0);
                acc1 = __builtin_amdgcn_mfma_f32_32x32x16_bf16(af[ks], vf1, acc1, 0, 0, 0);
            }
            __builtin_amdgcn_s_setprio(0);
        }
    }

    // full row-sum: partner lane holds the other half of the keys
    ls += __shfl_xor(ls, 32);

    // partial epilogue: acc row = q = crow(r,h), col = dh*32 + l32
#pragma unroll
    for (int r = 0; r < 16; ++r) {
        const int qrow = qb * 128 + wave * 32 + (r & 3) + 8 * (r >> 2) + 4 * h;
        float* pp = part + ((size_t)(b * SL + qrow) * 4 + c) * DH + l32;
        pp[0]  = acc0[r];
        pp[32] = acc1[r];
    }
    if (h == 0)
        lpart[(size_t)(b * SL + qg) * 4 + c] = ls;
}

// ---------------- combine ----------------
__global__ __launch_bounds__(256) void combine(
        const float* __restrict__ part, const float* __restrict__ lpart,
        float* __restrict__ O) {
    const int tid = threadIdx.x;
    const int r   = blockIdx.x * 16 + (tid >> 4);   // global row (b*2048+row)
    const int d4  = tid & 15;
    const int qb  = (r >> 7) & 15;
    const int nch = (2 * qb + 9) >> 3;              // ceil((2qb+2)/8)
    float4 s = make_float4(0.f, 0.f, 0.f, 0.f);
    float ls = 0.f;
    for (int c = 0; c < nch; ++c) {
        float4 p = *(const float4*)(part + ((size_t)r * 4 + c) * DH + d4 * 4);
        s.x += p.x; s.y += p.y; s.z += p.z; s.w += p.w;
        ls += lpart[(size_t)r * 4 + c];
    }
    const float inv = 1.0f / ls;
    float4 o; o.x = s.x * inv; o.y = s.y * inv; o.z = s.z * inv; o.w = s.w * inv;
    *(float4*)(O + (size_t)r * DH + d4 * 4) = o;
}

extern "C" void kernel_launch(void* const* d_in, const int* in_sizes, int n_in,
                              void* d_out, int out_size, void* d_ws, size_t ws_size,
                              hipStream_t stream) {
    const float* q = (const float*)d_in[0];
    const float* k = (const float*)d_in[1];
    const float* v = (const float*)d_in[2];
    float* o = (float*)d_out;
    __bf16* Kb   = (__bf16*)d_ws;                          // 4 MiB
    __bf16* Vt   = Kb + (size_t)NB * SL * DH;              // 4 MiB
    float*  pt   = (float*)((char*)d_ws + (8u << 20));     // 32 MiB partials
    float*  lp   = pt + (size_t)NB * SL * 4 * DH;          // 512 KiB
    hipLaunchKernelGGL(prepass, dim3(NB * 32), dim3(256), 0, stream, k, v, Kb, Vt);
    hipLaunchKernelGGL(attn_fwd, dim3(640), dim3(256), 0, stream, q, Kb, Vt, pt, lp);
    hipLaunchKernelGGL(combine, dim3(NB * SL / 16), dim3(256), 0, stream, pt, lp, o);
}